// Round 1
// baseline (395.003 us; speedup 1.0000x reference)
//
#include <hip/hip_runtime.h>
#include <hip/hip_bf16.h>
#include <cmath>

// out[b,o] = max(softplus(log_scale[o]),1e-4) * sum_k x[b,k]*W[o,k] + bias[o]
// B=32, K=N=8192. W ternary int32 [N,K] row-major: 268 MB -> memory-bound on W.
// Roofline: 268 MB / 6.3 TB/s ~= 43 us.
//
// Design: no LDS, no barriers. Each wave owns one 16-o n-tile and a K/4 chunk.
// B-frags loaded DIRECTLY from global in MFMA fragment order (2x int4 per 32-k),
// converted int->bf16 once in-register (cvt+v_perm), reused by both m-tiles.
// 2-kb ping-pong prefetch banks keep ~16 loads in flight per wave -> BW-saturated.

#define K_SZ   8192
#define N_SZ   8192
#define B_SZ   32
#define KSPLIT 4
#define KB_TOT (K_SZ / 32)         // 256 32-k blocks
#define KB_PER (KB_TOT / KSPLIT)   // 64 per wave

typedef __attribute__((ext_vector_type(8))) short bf16x8;   // MFMA A/B frag
typedef __attribute__((ext_vector_type(4))) float f32x4;    // MFMA C/D frag

// fp32 pair -> packed bf16 (round-half-up), lo in low 16
__device__ __forceinline__ unsigned pack_rn(float lo, float hi) {
  unsigned ul = __builtin_bit_cast(unsigned, lo) + 0x8000u;
  unsigned uh = __builtin_bit_cast(unsigned, hi) + 0x8000u;
  return (ul >> 16) | (uh & 0xFFFF0000u);
}
// ternary int pair -> packed bf16 (exact: +-1.0/0.0 truncate losslessly)
__device__ __forceinline__ unsigned pack_w(int w0, int w1) {
  unsigned u0 = __builtin_bit_cast(unsigned, (float)w0);
  unsigned u1 = __builtin_bit_cast(unsigned, (float)w1);
  return (u0 >> 16) | (u1 & 0xFFFF0000u);   // compiles to v_perm_b32
}

// Rearrange X fp32[32,8192] -> Xr bf16 chunks in MFMA A-frag order.
// Chunk c = kb*2 + mt: 1 KB where lane l holds
// X[mt*16 + (l&15)][kb*32 + (l>>4)*8 .. +8] as bf16x8.
__global__ void xprep(const float* __restrict__ X, uint4* __restrict__ Xr) {
  int t = blockIdx.x * blockDim.x + threadIdx.x;   // 0..32767
  int lane = t & 63;
  int chunk = t >> 6;                              // 0..511
  int kb = chunk >> 1;
  int mt = chunk & 1;
  int row = mt * 16 + (lane & 15);
  int k0 = kb * 32 + (lane >> 4) * 8;
  const float* p = X + (size_t)row * K_SZ + k0;
  float4 a = *(const float4*)p;
  float4 b = *(const float4*)(p + 4);
  uint4 o;
  o.x = pack_rn(a.x, a.y); o.y = pack_rn(a.z, a.w);
  o.z = pack_rn(b.x, b.y); o.w = pack_rn(b.z, b.w);
  Xr[t] = o;   // coalesced
}

__global__ __launch_bounds__(256, 2) void tmm(
    const int*   __restrict__ W,
    const uint4* __restrict__ Xr,
    const float* __restrict__ log_scale,
    const float* __restrict__ bias,
    float*       __restrict__ out) {
  const int tid  = threadIdx.x;
  const int w    = tid >> 6;       // wave 0..3
  const int lane = tid & 63;
  const int r    = lane & 15;      // -> o within n-tile (B/D col)
  const int q    = lane >> 4;      // -> k-subgroup   (D row group)
  const int ntg  = blockIdx.x * 4 + w;     // global n-tile 0..511
  const int o0   = ntg * 16;
  const int kb0  = blockIdx.y * KB_PER;
  const int kbEnd = kb0 + KB_PER;

  // B-frag source: lane l reads W[o0+r][kb*32 + q*8 .. +8] (2x int4).
  // The int4 pair covers each row's full 128 B per kb -> lines fully consumed.
  const int*   gW = W + (size_t)(o0 + r) * K_SZ + q * 8;
  const uint4* xA = Xr + lane;     // A chunks at (kb*2+mt)*64

  f32x4 acc0 = {0.f, 0.f, 0.f, 0.f};   // m-tile 0 (batch 0..15)
  f32x4 acc1 = {0.f, 0.f, 0.f, 0.f};   // m-tile 1 (batch 16..31)

  int4  wa0, wa1, wb0, wb1, wc0, wc1, wd0, wd1;   // W banks (named: no scratch)
  uint4 xa0, xa1, xb0, xb1, xc0, xc1, xd0, xd1;   // A banks

#define LDW(kb, lo, hi) { const int* g_ = gW + (size_t)(kb) * 32; \
    lo = *(const int4*)g_; hi = *(const int4*)(g_ + 4); }
#define LDA(kb, m0, m1) { const uint4* x_ = xA + (size_t)(kb) * 128; \
    m0 = x_[0]; m1 = x_[64]; }
#define COMP(lo, hi, m0, m1) { \
    union { unsigned u[4]; bf16x8 v; } Bf_; \
    Bf_.u[0] = pack_w(lo.x, lo.y); Bf_.u[1] = pack_w(lo.z, lo.w); \
    Bf_.u[2] = pack_w(hi.x, hi.y); Bf_.u[3] = pack_w(hi.z, hi.w); \
    acc0 = __builtin_amdgcn_mfma_f32_16x16x32_bf16( \
        __builtin_bit_cast(bf16x8, m0), Bf_.v, acc0, 0, 0, 0); \
    acc1 = __builtin_amdgcn_mfma_f32_16x16x32_bf16( \
        __builtin_bit_cast(bf16x8, m1), Bf_.v, acc1, 0, 0, 0); }

  // prologue: group 0 (kb0, kb0+1) into banks a/b
  LDW(kb0 + 0, wa0, wa1); LDW(kb0 + 1, wb0, wb1);
  LDA(kb0 + 0, xa0, xa1); LDA(kb0 + 1, xb0, xb1);

  for (int kb = kb0; kb < kbEnd; kb += 4) {
    // next group into c/d banks (kb+2, kb+3 always in range)
    LDW(kb + 2, wc0, wc1); LDW(kb + 3, wd0, wd1);
    LDA(kb + 2, xc0, xc1); LDA(kb + 3, xd0, xd1);
    COMP(wa0, wa1, xa0, xa1);
    COMP(wb0, wb1, xb0, xb1);
    // group after that into a/b banks (clamped on final iter; wasted L2-hot reads)
    int k4 = kb + 4 < kbEnd ? kb + 4 : kb0;
    int k5 = kb + 5 < kbEnd ? kb + 5 : kb0;
    LDW(k4, wa0, wa1); LDW(k5, wb0, wb1);
    LDA(k4, xa0, xa1); LDA(k5, xb0, xb1);
    COMP(wc0, wc1, xc0, xc1);
    COMP(wd0, wd1, xd0, xd1);
  }

  // epilogue: scale + bias, k-split combine via atomics (order-independent)
  const int o = o0 + r;
  float sp    = log1pf(expf(log_scale[o]));
  float scale = fmaxf(sp, 1e-4f);
  float badd  = (blockIdx.y == 0) ? bias[o] : 0.f;
  #pragma unroll
  for (int rg = 0; rg < 4; ++rg) {
    // C/D layout: col = lane&15 -> o, row = (lane>>4)*4 + reg -> batch
    atomicAdd(&out[(size_t)(q * 4 + rg) * N_SZ + o],      acc0[rg] * scale + badd);
    atomicAdd(&out[(size_t)(16 + q * 4 + rg) * N_SZ + o], acc1[rg] * scale + badd);
  }
#undef LDW
#undef LDA
#undef COMP
}

extern "C" void kernel_launch(void* const* d_in, const int* in_sizes, int n_in,
                              void* d_out, int out_size, void* d_ws, size_t ws_size,
                              hipStream_t stream) {
  const float* X  = (const float*)d_in[0];
  const float* ls = (const float*)d_in[1];
  const float* bs = (const float*)d_in[2];
  const int*   W  = (const int*)d_in[3];
  float* out = (float*)d_out;
  uint4* Xr = (uint4*)d_ws;   // 512 KB

  hipMemsetAsync(out, 0, (size_t)B_SZ * N_SZ * sizeof(float), stream);
  xprep<<<128, 256, 0, stream>>>(X, Xr);
  dim3 grid(N_SZ / 64, KSPLIT);   // 128 x 4 = 512 blocks -> 2 blocks/CU
  tmm<<<grid, 256, 0, stream>>>(W, Xr, ls, bs, out);
}

// Round 3
// 394.467 us; speedup vs baseline: 1.0014x; 1.0014x over previous
//
#include <hip/hip_runtime.h>
#include <hip/hip_bf16.h>
#include <cmath>

// out[b,o] = max(softplus(log_scale[o]),1e-4) * sum_k x[b,k]*W[o,k] + bias[o]
// B=32, K=N=8192. W ternary int32 [N,K] row-major: 268 MB -> memory-bound on W.
// Roofline: 268 MB / 6.3 TB/s ~= 43 us.
//
// Design: no LDS, no barriers. Each wave owns one 16-o n-tile and a K/8 chunk.
// B-frags loaded DIRECTLY from global in MFMA fragment order (2x 16B per 32-k),
// nontemporal (zero reuse -> don't evict Xr from L2/L3), converted int->bf16
// once in-register (cvt+v_perm), reused by both m-tiles. KSPLIT=8 -> 1024
// blocks = 4 blocks/CU = 4 waves/SIMD for latency hiding.

#define K_SZ   8192
#define N_SZ   8192
#define B_SZ   32
#define KSPLIT 8
#define KB_TOT (K_SZ / 32)         // 256 32-k blocks
#define KB_PER (KB_TOT / KSPLIT)   // 32 per wave

typedef __attribute__((ext_vector_type(8))) short bf16x8;   // MFMA A/B frag
typedef __attribute__((ext_vector_type(4))) float f32x4;    // MFMA C/D frag
typedef __attribute__((ext_vector_type(4))) int   i32x4;    // native 16B int vec
typedef __attribute__((ext_vector_type(4))) unsigned u32x4; // native 16B uint vec

// fp32 pair -> packed bf16 (round-half-up), lo in low 16
__device__ __forceinline__ unsigned pack_rn(float lo, float hi) {
  unsigned ul = __builtin_bit_cast(unsigned, lo) + 0x8000u;
  unsigned uh = __builtin_bit_cast(unsigned, hi) + 0x8000u;
  return (ul >> 16) | (uh & 0xFFFF0000u);
}
// ternary int pair -> packed bf16 (exact: +-1.0/0.0 truncate losslessly)
__device__ __forceinline__ unsigned pack_w(int w0, int w1) {
  unsigned u0 = __builtin_bit_cast(unsigned, (float)w0);
  unsigned u1 = __builtin_bit_cast(unsigned, (float)w1);
  return (u0 >> 16) | (u1 & 0xFFFF0000u);   // compiles to v_perm_b32
}

// Rearrange X fp32[32,8192] -> Xr bf16 chunks in MFMA A-frag order.
// Chunk c = kb*2 + mt: 1 KB where lane l holds
// X[mt*16 + (l&15)][kb*32 + (l>>4)*8 .. +8] as bf16x8.
__global__ void xprep(const float* __restrict__ X, u32x4* __restrict__ Xr) {
  int t = blockIdx.x * blockDim.x + threadIdx.x;   // 0..32767
  int lane = t & 63;
  int chunk = t >> 6;                              // 0..511
  int kb = chunk >> 1;
  int mt = chunk & 1;
  int row = mt * 16 + (lane & 15);
  int k0 = kb * 32 + (lane >> 4) * 8;
  const float* p = X + (size_t)row * K_SZ + k0;
  float4 a = *(const float4*)p;
  float4 b = *(const float4*)(p + 4);
  u32x4 o;
  o.x = pack_rn(a.x, a.y); o.y = pack_rn(a.z, a.w);
  o.z = pack_rn(b.x, b.y); o.w = pack_rn(b.z, b.w);
  Xr[t] = o;   // coalesced
}

__global__ __launch_bounds__(256, 4) void tmm(
    const int*   __restrict__ W,
    const u32x4* __restrict__ Xr,
    const float* __restrict__ log_scale,
    const float* __restrict__ bias,
    float*       __restrict__ out) {
  const int tid  = threadIdx.x;
  const int w    = tid >> 6;       // wave 0..3
  const int lane = tid & 63;
  const int r    = lane & 15;      // -> o within n-tile (B/D col)
  const int q    = lane >> 4;      // -> k-subgroup   (D row group)
  const int ntg  = blockIdx.x * 4 + w;     // global n-tile 0..511
  const int o0   = ntg * 16;
  const int kb0  = blockIdx.y * KB_PER;
  const int kbEnd = kb0 + KB_PER;

  // B-frag source: lane l reads W[o0+r][kb*32 + q*8 .. +8] (2x 16B).
  // The pair covers each row's full 128 B per kb -> lines fully consumed.
  const int*   gW = W + (size_t)(o0 + r) * K_SZ + q * 8;
  const u32x4* xA = Xr + lane;     // A chunks at (kb*2+mt)*64

  f32x4 acc0 = {0.f, 0.f, 0.f, 0.f};   // m-tile 0 (batch 0..15)
  f32x4 acc1 = {0.f, 0.f, 0.f, 0.f};   // m-tile 1 (batch 16..31)

  i32x4 wa0, wa1, wb0, wb1, wc0, wc1, wd0, wd1;   // W banks (named: no scratch)
  u32x4 xa0, xa1, xb0, xb1, xc0, xc1, xd0, xd1;   // A banks

  // W: nontemporal (stream, zero reuse). A: normal (keep Xr L2-resident).
#define LDW(kb, lo, hi) { const i32x4* g_ = (const i32x4*)(gW + (size_t)(kb) * 32); \
    lo = __builtin_nontemporal_load(g_); hi = __builtin_nontemporal_load(g_ + 1); }
#define LDA(kb, m0, m1) { const u32x4* x_ = xA + (size_t)(kb) * 128; \
    m0 = x_[0]; m1 = x_[64]; }
#define COMP(lo, hi, m0, m1) { \
    union { unsigned u[4]; bf16x8 v; } Bf_; \
    Bf_.u[0] = pack_w(lo.x, lo.y); Bf_.u[1] = pack_w(lo.z, lo.w); \
    Bf_.u[2] = pack_w(hi.x, hi.y); Bf_.u[3] = pack_w(hi.z, hi.w); \
    acc0 = __builtin_amdgcn_mfma_f32_16x16x32_bf16( \
        __builtin_bit_cast(bf16x8, m0), Bf_.v, acc0, 0, 0, 0); \
    acc1 = __builtin_amdgcn_mfma_f32_16x16x32_bf16( \
        __builtin_bit_cast(bf16x8, m1), Bf_.v, acc1, 0, 0, 0); }

  // prologue: group 0 (kb0, kb0+1) into banks a/b
  LDW(kb0 + 0, wa0, wa1); LDW(kb0 + 1, wb0, wb1);
  LDA(kb0 + 0, xa0, xa1); LDA(kb0 + 1, xb0, xb1);

  for (int kb = kb0; kb < kbEnd; kb += 4) {
    // next group into c/d banks (kb+2, kb+3 always in range)
    LDW(kb + 2, wc0, wc1); LDW(kb + 3, wd0, wd1);
    LDA(kb + 2, xc0, xc1); LDA(kb + 3, xd0, xd1);
    COMP(wa0, wa1, xa0, xa1);
    COMP(wb0, wb1, xb0, xb1);
    // group after that into a/b banks (clamped on final iter; wasted L2-hot reads)
    int k4 = kb + 4 < kbEnd ? kb + 4 : kb0;
    int k5 = kb + 5 < kbEnd ? kb + 5 : kb0;
    LDW(k4, wa0, wa1); LDW(k5, wb0, wb1);
    LDA(k4, xa0, xa1); LDA(k5, xb0, xb1);
    COMP(wc0, wc1, xc0, xc1);
    COMP(wd0, wd1, xd0, xd1);
  }

  // epilogue: scale + bias, k-split combine via atomics (order-independent)
  const int o = o0 + r;
  float sp    = log1pf(expf(log_scale[o]));
  float scale = fmaxf(sp, 1e-4f);
  float badd  = (blockIdx.y == 0) ? bias[o] : 0.f;
  #pragma unroll
  for (int rg = 0; rg < 4; ++rg) {
    // C/D layout: col = lane&15 -> o, row = (lane>>4)*4 + reg -> batch
    atomicAdd(&out[(size_t)(q * 4 + rg) * N_SZ + o],      acc0[rg] * scale + badd);
    atomicAdd(&out[(size_t)(16 + q * 4 + rg) * N_SZ + o], acc1[rg] * scale + badd);
  }
#undef LDW
#undef LDA
#undef COMP
}

extern "C" void kernel_launch(void* const* d_in, const int* in_sizes, int n_in,
                              void* d_out, int out_size, void* d_ws, size_t ws_size,
                              hipStream_t stream) {
  const float* X  = (const float*)d_in[0];
  const float* ls = (const float*)d_in[1];
  const float* bs = (const float*)d_in[2];
  const int*   W  = (const int*)d_in[3];
  float* out = (float*)d_out;
  u32x4* Xr = (u32x4*)d_ws;   // 512 KB

  (void)hipMemsetAsync(out, 0, (size_t)B_SZ * N_SZ * sizeof(float), stream);
  xprep<<<128, 256, 0, stream>>>(X, Xr);
  dim3 grid(N_SZ / 64, KSPLIT);   // 128 x 8 = 1024 blocks -> 4 blocks/CU
  tmm<<<grid, 256, 0, stream>>>(W, Xr, ls, bs, out);
}

// Round 4
// 369.874 us; speedup vs baseline: 1.0679x; 1.0665x over previous
//
#include <hip/hip_runtime.h>
#include <hip/hip_bf16.h>
#include <cmath>

// out[b,o] = max(softplus(log_scale[o]),1e-4) * sum_k x[b,k]*W[o,k] + bias[o]
// B=32, K=N=8192. W ternary int32 [N,K] row-major. Memory-bound on W (256 MB/launch).
//
// Proven-structure kernel (366 us session best): LDS-staged W with 2-row
// lane-contiguous 1 KB staging loads (DRAM page-friendly: 512 B/row/step,
// ~16-32K concurrent stream positions). Round-3 lesson: direct 16-row x 128 B
// fragment scatter regresses ~29 us (HBM row-buffer thrash) and is insensitive
// to occupancy/NT -> keep staged pattern. This round's single delta vs the
// 366 us baseline: KSPLIT 2->4 (4 blocks/CU, 4 waves/SIMD) to overlap the
// per-step barrier drain across more resident blocks.

#define K_SZ   8192
#define N_SZ   8192
#define B_SZ   32
#define KSPLIT 4
#define KCH    (K_SZ / KSPLIT)   // 2048 k per block
#define BN     32                // output cols per block
#define BK     128               // K ints per staged step
#define STEPS  (KCH / BK)        // 16
#define LDW    132               // padded LDS row stride in ints (132 = 4*33, int4-aligned)

typedef __attribute__((ext_vector_type(8))) short bf16x8;   // MFMA A/B frag
typedef __attribute__((ext_vector_type(4))) float f32x4;    // MFMA C/D frag

// fp32 pair -> packed bf16 (round-half-up), lo in low 16
__device__ __forceinline__ unsigned pack_rn(float lo, float hi) {
  unsigned ul = __builtin_bit_cast(unsigned, lo) + 0x8000u;
  unsigned uh = __builtin_bit_cast(unsigned, hi) + 0x8000u;
  return (ul >> 16) | (uh & 0xFFFF0000u);
}
// ternary int pair -> packed bf16 (exact)
__device__ __forceinline__ unsigned pack_w(int w0, int w1) {
  unsigned u0 = __builtin_bit_cast(unsigned, (float)w0);
  unsigned u1 = __builtin_bit_cast(unsigned, (float)w1);
  return (u0 >> 16) | (u1 & 0xFFFF0000u);   // v_cvt x2 + v_perm
}

// Rearrange X fp32[32,8192] -> Xr bf16 chunks in MFMA A-frag order.
// Chunk c = kb*2 + mt (kb = 32-k block 0..255, mt = m-tile 0..1): 1 KB where
// lane l holds X[mt*16 + (l&15)][kb*32 + (l>>4)*8 .. +8] as bf16x8.
__global__ void xprep(const float* __restrict__ X, uint4* __restrict__ Xr) {
  int t = blockIdx.x * blockDim.x + threadIdx.x;   // 0..32767
  int lane = t & 63;
  int chunk = t >> 6;                              // 0..511
  int kb = chunk >> 1;
  int mt = chunk & 1;
  int row = mt * 16 + (lane & 15);
  int k0 = kb * 32 + (lane >> 4) * 8;
  const float* p = X + (size_t)row * K_SZ + k0;
  float4 a = *(const float4*)p;
  float4 b = *(const float4*)(p + 4);
  uint4 o;
  o.x = pack_rn(a.x, a.y); o.y = pack_rn(a.z, a.w);
  o.z = pack_rn(b.x, b.y); o.w = pack_rn(b.z, b.w);
  Xr[t] = o;   // coalesced
}

__global__ __launch_bounds__(256, 4) void tmm(
    const int*   __restrict__ W,
    const uint4* __restrict__ Xr,
    const float* __restrict__ log_scale,
    const float* __restrict__ bias,
    float*       __restrict__ out) {
  __shared__ int lds[32 * LDW];   // 16,896 B -> 4 blocks/CU fits (67.6 KB)

  const int tid  = threadIdx.x;
  const int w    = tid >> 6;       // wave 0..3
  const int lane = tid & 63;
  const int q    = lane >> 4;
  const int r    = lane & 15;
  const int nb   = blockIdx.x * BN;
  const int kh   = blockIdx.y;     // k-chunk index
  const int mt   = w & 1;          // wave's m-tile (batch 16-group)
  const int nt   = w >> 1;         // wave's n-tile

  // --- W staging addresses: wave w stages rows 8w..8w+7, 4 issues x 2 rows.
  // Lane-contiguous: lanes 0..31 -> row (8w+2i), ints 4*(l&31); lanes 32..63 -> row+1.
  const int srow = 8 * w + (lane >> 5);
  const int skof = 4 * (lane & 31);
  const int* gW = W + (size_t)(nb + srow) * K_SZ + (size_t)kh * KCH + skof;
  const int lof = srow * LDW + skof;

  // prologue: load step 0 W regs
  int4 wr0 = *(const int4*)(gW + 0 * 2 * K_SZ);
  int4 wr1 = *(const int4*)(gW + 1 * 2 * K_SZ);
  int4 wr2 = *(const int4*)(gW + 2 * 2 * K_SZ);
  int4 wr3 = *(const int4*)(gW + 3 * 2 * K_SZ);

  // prologue: A frags for step 0 (contiguous 1 KB wave-loads, L2-hot)
  const uint4* xr = Xr + lane;
  const int kbb = kh * (KCH / 32);       // base 32-k block index
  uint4 a0 = xr[(size_t)((kbb + 0) * 2 + mt) * 64];
  uint4 a1 = xr[(size_t)((kbb + 1) * 2 + mt) * 64];
  uint4 a2 = xr[(size_t)((kbb + 2) * 2 + mt) * 64];
  uint4 a3 = xr[(size_t)((kbb + 3) * 2 + mt) * 64];

  f32x4 acc = {0.f, 0.f, 0.f, 0.f};
  const int Rbase = (nt * 16 + r) * LDW;

  for (int step = 0; step < STEPS; ++step) {
    __syncthreads();                       // prev step's LDS consumers done
    *(int4*)&lds[lof + 0 * 2 * LDW] = wr0;
    *(int4*)&lds[lof + 1 * 2 * LDW] = wr1;
    *(int4*)&lds[lof + 2 * 2 * LDW] = wr2;
    *(int4*)&lds[lof + 3 * 2 * LDW] = wr3;
    if (step + 1 < STEPS) {                // prefetch next W: in flight across compute
      const int* g = gW + (step + 1) * BK;
      wr0 = *(const int4*)(g + 0 * 2 * K_SZ);
      wr1 = *(const int4*)(g + 1 * 2 * K_SZ);
      wr2 = *(const int4*)(g + 2 * 2 * K_SZ);
      wr3 = *(const int4*)(g + 3 * 2 * K_SZ);
    }
    __syncthreads();                       // LDS writes visible

    uint4 ca0 = a0, ca1 = a1, ca2 = a2, ca3 = a3;
    if (step + 1 < STEPS) {                // prefetch next A frags
      int kb2 = kbb + (step + 1) * 4;
      a0 = xr[(size_t)((kb2 + 0) * 2 + mt) * 64];
      a1 = xr[(size_t)((kb2 + 1) * 2 + mt) * 64];
      a2 = xr[(size_t)((kb2 + 2) * 2 + mt) * 64];
      a3 = xr[(size_t)((kb2 + 3) * 2 + mt) * 64];
    }

    #pragma unroll
    for (int s = 0; s < 4; ++s) {
      uint4 ca = (s == 0) ? ca0 : (s == 1) ? ca1 : (s == 2) ? ca2 : ca3;
      int ro = Rbase + s * 32 + q * 8;
      int4 b0 = *(const int4*)&lds[ro];
      int4 b1 = *(const int4*)&lds[ro + 4];
      union { unsigned u[4]; bf16x8 v; } Bf;
      Bf.u[0] = pack_w(b0.x, b0.y); Bf.u[1] = pack_w(b0.z, b0.w);
      Bf.u[2] = pack_w(b1.x, b1.y); Bf.u[3] = pack_w(b1.z, b1.w);
      bf16x8 Af = __builtin_bit_cast(bf16x8, ca);
      acc = __builtin_amdgcn_mfma_f32_16x16x32_bf16(Af, Bf.v, acc, 0, 0, 0);
    }
  }

  // epilogue: scale + bias, k-split combine via atomics (order-independent)
  const int o = nb + nt * 16 + r;
  float sp    = log1pf(expf(log_scale[o]));
  float scale = fmaxf(sp, 1e-4f);
  float badd  = (kh == 0) ? bias[o] : 0.f;
  #pragma unroll
  for (int rg = 0; rg < 4; ++rg) {
    int b = mt * 16 + q * 4 + rg;   // C/D layout: row=(lane>>4)*4+reg -> batch, col=lane&15 -> o
    atomicAdd(&out[(size_t)b * N_SZ + o], acc[rg] * scale + badd);
  }
}

extern "C" void kernel_launch(void* const* d_in, const int* in_sizes, int n_in,
                              void* d_out, int out_size, void* d_ws, size_t ws_size,
                              hipStream_t stream) {
  const float* X  = (const float*)d_in[0];
  const float* ls = (const float*)d_in[1];
  const float* bs = (const float*)d_in[2];
  const int*   W  = (const int*)d_in[3];
  float* out = (float*)d_out;
  uint4* Xr = (uint4*)d_ws;   // 512 KB

  (void)hipMemsetAsync(out, 0, (size_t)B_SZ * N_SZ * sizeof(float), stream);
  xprep<<<128, 256, 0, stream>>>(X, Xr);
  dim3 grid(N_SZ / BN, KSPLIT);   // 256 x 4 = 1024 blocks -> 4 blocks/CU
  tmm<<<grid, 256, 0, stream>>>(W, Xr, ls, bs, out);
}